// Round 6
// baseline (254.123 us; speedup 1.0000x reference)
//
#include <hip/hip_runtime.h>
#include <math.h>

typedef _Float16 half2_t __attribute__((ext_vector_type(2)));

#define CEXP 2.8853900817779268f  // 2*log2(e): tanh(z) = 1 - 2/(2^(c*z)+1)
#define TABN 2048                 // s(theta) table cells (TABN+1 entries)

// Prepped-weight storage (rewritten by prep_kernel on every launch).
// w-MLP matrices stored [kk][j] so the unrolled j-inner loop reads consecutive
// dwords. phi-MLP is folded into the 1-D s(theta) table g_stab.
__device__ float   g_w1s[60];    // c*Ww1  [2][30]
__device__ float   g_b1s[30];    // c*bw1
__device__ half2_t g_w2p[450];   // [kk=15][j=30]: {c*W2[2kk][j], c*W2[2kk+1][j]}
__device__ float   g_b2s[30];
__device__ half2_t g_w3p[450];   // [kk=15][j=30]
__device__ float   g_b3s[30];
__device__ half2_t g_w4p[120];   // [kk=15][j=8] (unscaled)
__device__ float   g_stab[TABN + 1];  // s(theta(p)), p = diamond angle in [-2,2]

static __device__ __forceinline__ float fdot2(half2_t a, half2_t b, float c) {
#if __has_builtin(__builtin_amdgcn_fdot2)
    return __builtin_amdgcn_fdot2(a, b, c, false);
#else
    return fmaf((float)a.x, (float)b.x, fmaf((float)a.y, (float)b.y, c));
#endif
}

static __device__ __forceinline__ half2_t pkrtz(float a, float b) {
    return __builtin_bit_cast(half2_t, __builtin_amdgcn_cvt_pkrtz(a, b));
}

// tanh with the 2*log2(e) factor pre-folded into the incoming accumulator.
static __device__ __forceinline__ float tanh_pre(float z) {
    float e = __builtin_amdgcn_exp2f(z);
    float r = __builtin_amdgcn_rcpf(e + 1.0f);
    return fmaf(-2.0f, r, 1.0f);
}

// blocks 1..8: s(theta) table entries; block 0 additionally packs w-weights.
__global__ __launch_bounds__(256) void prep_kernel(
    const float* __restrict__ Ww1, const float* __restrict__ bw1,
    const float* __restrict__ Ww2, const float* __restrict__ bw2,
    const float* __restrict__ Ww3, const float* __restrict__ bw3,
    const float* __restrict__ Ww4,
    const float* __restrict__ Wp1, const float* __restrict__ bp1,
    const float* __restrict__ Wp2, const float* __restrict__ bp2,
    const float* __restrict__ Wp3, const float* __restrict__ bp3,
    const float* __restrict__ Wp4, const float* __restrict__ bp4)
{
    const int t = threadIdx.x;
    const int g = blockIdx.x * 256 + t;
    const float c = CEXP;

    // ---------- s(theta) table ----------
    if (g <= TABN) {
        const float pth = -2.0f + (4.0f / (float)TABN) * (float)g;
        float th;
        if (pth >= -1.0f && pth <= 1.0f) {
            th = atanf(pth / (1.0f - fabsf(pth)));      // /0 -> inf -> atan=pi/2 ok
        } else if (pth > 1.0f) {
            const float uu = 2.0f - pth;                // [0,1)
            th = (float)M_PI - atanf(uu / (1.0f - uu));
        } else {
            const float uu = -2.0f - pth;               // (-1,0]
            th = -(float)M_PI + atanf(-uu / (1.0f + uu));
        }
        const float cth = cosf(th), sth = sinf(th);

        // phi-MLP in f32 with exact tanh: 2 -> 15 -> 15 -> 15 -> 4
        float h[15], h2[15];
        for (int j = 0; j < 15; ++j)
            h[j] = tanhf(cth * Wp1[j] + sth * Wp1[15 + j] + bp1[j]);
        for (int j = 0; j < 15; ++j) {
            float a = bp2[j];
            for (int k = 0; k < 15; ++k) a += h[k] * Wp2[k * 15 + j];
            h2[j] = tanhf(a);
        }
        for (int j = 0; j < 15; ++j) {
            float a = bp3[j];
            for (int k = 0; k < 15; ++k) a += h2[k] * Wp3[k * 15 + j];
            h[j] = tanhf(a);
        }
        float ph[4];
        for (int j = 0; j < 4; ++j) {
            float a = bp4[j];
            for (int k = 0; k < 15; ++k) a += h[k] * Wp4[k * 4 + j];
            ph[j] = a;
        }
        const float s = ph[0] + ph[1] * sinf(0.5f * th) + ph[2] * sth
                      + ph[3] * sinf(1.5f * th);
        g_stab[g] = s;
    }

    // ---------- w-MLP weight packing (block 0 only) ----------
    if (blockIdx.x == 0) {
        for (int e = t; e < 450; e += 256) {
            int kk = e / 30, j = e % 30;
            half2_t h2v, h3v;
            h2v.x = (_Float16)(c * Ww2[(2 * kk) * 30 + j]);
            h2v.y = (_Float16)(c * Ww2[(2 * kk + 1) * 30 + j]);
            h3v.x = (_Float16)(c * Ww3[(2 * kk) * 30 + j]);
            h3v.y = (_Float16)(c * Ww3[(2 * kk + 1) * 30 + j]);
            g_w2p[e] = h2v;
            g_w3p[e] = h3v;
        }
        for (int e = t; e < 120; e += 256) {
            int kk4 = e / 8, j4 = e % 8;
            half2_t h4;
            h4.x = (_Float16)Ww4[(2 * kk4) * 8 + j4];
            h4.y = (_Float16)Ww4[(2 * kk4 + 1) * 8 + j4];
            g_w4p[e] = h4;
        }
        if (t < 60) g_w1s[t] = c * Ww1[t];
        if (t < 30) {
            g_b1s[t] = c * bw1[t];
            g_b2s[t] = c * bw2[t];
            g_b3s[t] = c * bw3[t];
        }
    }
}

// 2 points per thread; 30-wide layers processed in j-halves (16+14).
__global__ __launch_bounds__(256, 4) void interior_kernel(
    const float4* __restrict__ x,      // two points per float4
    const float*  __restrict__ imv,
    const float*  __restrict__ lmbd,
    const float*  __restrict__ bw4,
    float* __restrict__ out, int n2)   // n2 = n/2
{
    const int idx = blockIdx.x * blockDim.x + threadIdx.x;
    if (idx >= n2) return;

    const float4 xx = x[idx];
    const float X0[2] = {xx.x, xx.z};
    const float X1[2] = {xx.y, xx.w};

    // ========== w-MLP layer 1 (f32, prescaled): 2 -> 30, tanh, pack ==========
    half2_t apk[2][15];
    #pragma unroll
    for (int jj = 0; jj < 15; ++jj) {
        const int j0 = 2 * jj, j1 = 2 * jj + 1;
        const float wa0 = g_w1s[j0], wb0 = g_w1s[30 + j0], bb0 = g_b1s[j0];
        const float wa1 = g_w1s[j1], wb1 = g_w1s[30 + j1], bb1 = g_b1s[j1];
        #pragma unroll
        for (int p = 0; p < 2; ++p) {
            const float t0 = tanh_pre(fmaf(X1[p], wb0, fmaf(X0[p], wa0, bb0)));
            const float t1 = tanh_pre(fmaf(X1[p], wb1, fmaf(X0[p], wa1, bb1)));
            apk[p][jj] = pkrtz(t0, t1);
        }
    }

    // ========== layers 2 and 3 (fp16 dot2, f32 accum), j-halved ==========
    half2_t bpk[2][15];
    #pragma unroll
    for (int layer = 0; layer < 2; ++layer) {
        const half2_t* __restrict__ W = layer ? g_w3p : g_w2p;
        const float*   __restrict__ B = layer ? g_b3s : g_b2s;

        // ---- half 0: j = 0..15 ----
        {
            float a16[2][16];
            #pragma unroll
            for (int j = 0; j < 16; ++j) {
                const float bb = B[j];
                a16[0][j] = bb; a16[1][j] = bb;
            }
            #pragma unroll
            for (int kk = 0; kk < 15; ++kk) {
                #pragma unroll
                for (int j = 0; j < 16; ++j) {
                    const half2_t w = W[kk * 30 + j];
                    a16[0][j] = fdot2(apk[0][kk], w, a16[0][j]);
                    a16[1][j] = fdot2(apk[1][kk], w, a16[1][j]);
                }
            }
            #pragma unroll
            for (int p = 0; p < 2; ++p)
                #pragma unroll
                for (int jj = 0; jj < 8; ++jj)
                    bpk[p][jj] = pkrtz(tanh_pre(a16[p][2 * jj]),
                                       tanh_pre(a16[p][2 * jj + 1]));
        }
        // ---- half 1: j = 16..29 ----
        {
            float a14[2][14];
            #pragma unroll
            for (int j = 0; j < 14; ++j) {
                const float bb = B[16 + j];
                a14[0][j] = bb; a14[1][j] = bb;
            }
            #pragma unroll
            for (int kk = 0; kk < 15; ++kk) {
                #pragma unroll
                for (int j = 0; j < 14; ++j) {
                    const half2_t w = W[kk * 30 + 16 + j];
                    a14[0][j] = fdot2(apk[0][kk], w, a14[0][j]);
                    a14[1][j] = fdot2(apk[1][kk], w, a14[1][j]);
                }
            }
            #pragma unroll
            for (int p = 0; p < 2; ++p)
                #pragma unroll
                for (int jj = 0; jj < 7; ++jj)
                    bpk[p][8 + jj] = pkrtz(tanh_pre(a14[p][2 * jj]),
                                           tanh_pre(a14[p][2 * jj + 1]));
        }
        // feed next layer
        #pragma unroll
        for (int p = 0; p < 2; ++p)
            #pragma unroll
            for (int kk = 0; kk < 15; ++kk)
                apk[p][kk] = bpk[p][kk];
    }

    // ========== layer 4 (fp16 dot2, unscaled): 30 -> 8 ==========
    float wv[2][8];
    #pragma unroll
    for (int j = 0; j < 8; ++j) {
        const float bb = bw4[j];
        wv[0][j] = bb; wv[1][j] = bb;
    }
    #pragma unroll
    for (int kk = 0; kk < 15; ++kk) {
        #pragma unroll
        for (int j = 0; j < 8; ++j) {
            const half2_t w = g_w4p[kk * 8 + j];
            wv[0][j] = fdot2(apk[0][kk], w, wv[0][j]);
            wv[1][j] = fdot2(apk[1][kk], w, wv[1][j]);
        }
    }

    // ========== geometry + phi-table + singular + combine ==========
    const float im0 = imv[0], im1 = imv[1], lam = lmbd[0];
    float res[2];
    #pragma unroll
    for (int p = 0; p < 2; ++p) {
        const float x0 = X0[p], x1 = X1[p];
        const float dx = x0 - im0, dy = x1 - im1;
        const float r  = sqrtf(fmaf(dx, dx, dy * dy));

        // yita(r)
        const float t  = fminf(fmaxf(fmaf(2.5f, r, -1.25f), 0.0f), 1.0f);
        const float t3 = t * t * t;
        const float yv = fmaf(fmaf(fmaf(-6.0f, t, 15.0f), t, -10.0f), t3, 1.0f);

        // r^lambda (sqrt fast path for lambda == 0.5)
        float rl;
        if (lam == 0.5f) rl = sqrtf(r);
        else rl = __builtin_amdgcn_exp2f(lam * __builtin_amdgcn_logf(fmaxf(r, 1e-20f)));

        // diamond-angle parameter p(theta) in [-2,2], no trig
        const float l1n = fmaxf(fabsf(dx) + fabsf(dy), 1e-20f);
        const float u   = dy * __builtin_amdgcn_rcpf(l1n);
        const float pbk = (dy >= 0.0f) ? (2.0f - u) : (-2.0f - u);
        const float pth = (dx >= 0.0f) ? u : pbk;

        // table lerp: s(theta)
        const float fi = fminf(fmaxf(fmaf(pth, (float)(TABN / 4), (float)(TABN / 2)),
                                     0.0f), (float)TABN - 0.001f);
        const int   ii = (int)fi;
        const float fr = fi - (float)ii;
        const float sv0 = g_stab[ii];
        const float sv1 = g_stab[ii + 1];
        const float sval = fmaf(fr, sv1 - sv0, sv0);

        // singular functions at x (about origin), algebraically reduced:
        // vp0 = r0^0.5 sin(th/2) = copysign(sqrt((r0-x0)/2), x1)
        // vp1 = x1
        // vp2 = r0^1.5 sin(1.5 th) = x1*sqrt((r0+x0)/2) + x0*vp0
        const float r0 = sqrtf(fmaf(x0, x0, x1 * x1));
        const float A  = sqrtf(fmaxf(0.0f, (r0 - x0) * 0.5f));
        const float Bq = sqrtf(fmaxf(0.0f, (r0 + x0) * 0.5f));
        const float vp0 = copysignf(A, x1);
        const float vp2 = fmaf(x1, Bq, x0 * vp0);

        float rp = fmaf(yv, wv[p][4], wv[p][0]);
        rp = fmaf(fmaf(wv[p][5], yv, wv[p][1]), vp0, rp);
        rp = fmaf(fmaf(wv[p][6], yv, wv[p][2]), x1, rp);
        rp = fmaf(fmaf(wv[p][7], yv, wv[p][3]), vp2, rp);

        res[p] = fmaf(sval * yv, rl, rp);
    }

    // contiguous pair store
    float2 o; o.x = res[0]; o.y = res[1];
    ((float2*)out)[idx] = o;
}

extern "C" void kernel_launch(void* const* d_in, const int* in_sizes, int n_in,
                              void* d_out, int out_size, void* d_ws, size_t ws_size,
                              hipStream_t stream) {
    const float4* x   = (const float4*)d_in[0];
    const float* imv  = (const float*)d_in[1];
    const float* lmbd = (const float*)d_in[2];
    const float* Ww1  = (const float*)d_in[3];
    const float* bw1  = (const float*)d_in[4];
    const float* Ww2  = (const float*)d_in[5];
    const float* bw2  = (const float*)d_in[6];
    const float* Ww3  = (const float*)d_in[7];
    const float* bw3  = (const float*)d_in[8];
    const float* Ww4  = (const float*)d_in[9];
    const float* bw4  = (const float*)d_in[10];
    const float* Wp1  = (const float*)d_in[11];
    const float* bp1  = (const float*)d_in[12];
    const float* Wp2  = (const float*)d_in[13];
    const float* bp2  = (const float*)d_in[14];
    const float* Wp3  = (const float*)d_in[15];
    const float* bp3  = (const float*)d_in[16];
    const float* Wp4  = (const float*)d_in[17];
    const float* bp4  = (const float*)d_in[18];
    float* out = (float*)d_out;

    const int n  = in_sizes[0] / 2;
    const int n2 = n / 2;

    // 9 blocks cover TABN+1 = 2049 table entries; block 0 also packs weights.
    prep_kernel<<<9, 256, 0, stream>>>(Ww1, bw1, Ww2, bw2, Ww3, bw3, Ww4,
                                       Wp1, bp1, Wp2, bp2, Wp3, bp3, Wp4, bp4);

    const int block = 256;
    const int grid = (n2 + block - 1) / block;
    interior_kernel<<<grid, block, 0, stream>>>(
        x, imv, lmbd, bw4, out, n2);
}

// Round 7
// 253.323 us; speedup vs baseline: 1.0032x; 1.0032x over previous
//
#include <hip/hip_runtime.h>
#include <math.h>

typedef _Float16 half2_t __attribute__((ext_vector_type(2)));

#define CEXP 2.8853900817779268f  // 2*log2(e): tanh(z) = 1 - 2/(2^(c*z)+1)
#define TABN 2048                 // s(theta) table cells (TABN+1 entries)

// Prepped-weight storage (rewritten by prep_kernel on every launch).
// w-MLP matrices stored [kk][j] so the unrolled j-inner loop reads consecutive
// dwords. phi-MLP is folded into the 1-D s(theta) table g_stab.
__device__ float   g_w1s[60];    // c*Ww1  [2][30]
__device__ float   g_b1s[30];    // c*bw1
__device__ half2_t g_w2p[450];   // [kk=15][j=30]: {c*W2[2kk][j], c*W2[2kk+1][j]}
__device__ float   g_b2s[30];
__device__ half2_t g_w3p[450];   // [kk=15][j=30]
__device__ float   g_b3s[30];
__device__ half2_t g_w4p[120];   // [kk=15][j=8] (unscaled)
__device__ float   g_stab[TABN + 1];  // s(theta(p)), p = diamond angle in [-2,2]

static __device__ __forceinline__ float fdot2(half2_t a, half2_t b, float c) {
#if __has_builtin(__builtin_amdgcn_fdot2)
    return __builtin_amdgcn_fdot2(a, b, c, false);
#else
    return fmaf((float)a.x, (float)b.x, fmaf((float)a.y, (float)b.y, c));
#endif
}

static __device__ __forceinline__ half2_t pkrtz(float a, float b) {
    return __builtin_bit_cast(half2_t, __builtin_amdgcn_cvt_pkrtz(a, b));
}

// tanh with the 2*log2(e) factor pre-folded into the incoming accumulator.
static __device__ __forceinline__ float tanh_pre(float z) {
    float e = __builtin_amdgcn_exp2f(z);
    float r = __builtin_amdgcn_rcpf(e + 1.0f);
    return fmaf(-2.0f, r, 1.0f);
}

// blocks 1..8: s(theta) table entries; block 0 additionally packs w-weights.
__global__ __launch_bounds__(256) void prep_kernel(
    const float* __restrict__ Ww1, const float* __restrict__ bw1,
    const float* __restrict__ Ww2, const float* __restrict__ bw2,
    const float* __restrict__ Ww3, const float* __restrict__ bw3,
    const float* __restrict__ Ww4,
    const float* __restrict__ Wp1, const float* __restrict__ bp1,
    const float* __restrict__ Wp2, const float* __restrict__ bp2,
    const float* __restrict__ Wp3, const float* __restrict__ bp3,
    const float* __restrict__ Wp4, const float* __restrict__ bp4)
{
    const int t = threadIdx.x;
    const int g = blockIdx.x * 256 + t;
    const float c = CEXP;

    // ---------- s(theta) table ----------
    if (g <= TABN) {
        const float pth = -2.0f + (4.0f / (float)TABN) * (float)g;
        float th;
        if (pth >= -1.0f && pth <= 1.0f) {
            th = atanf(pth / (1.0f - fabsf(pth)));      // /0 -> inf -> atan=pi/2 ok
        } else if (pth > 1.0f) {
            const float uu = 2.0f - pth;                // [0,1)
            th = (float)M_PI - atanf(uu / (1.0f - uu));
        } else {
            const float uu = -2.0f - pth;               // (-1,0]
            th = -(float)M_PI + atanf(-uu / (1.0f + uu));
        }
        const float cth = cosf(th), sth = sinf(th);

        // phi-MLP in f32 with exact tanh: 2 -> 15 -> 15 -> 15 -> 4
        float h[15], h2[15];
        for (int j = 0; j < 15; ++j)
            h[j] = tanhf(cth * Wp1[j] + sth * Wp1[15 + j] + bp1[j]);
        for (int j = 0; j < 15; ++j) {
            float a = bp2[j];
            for (int k = 0; k < 15; ++k) a += h[k] * Wp2[k * 15 + j];
            h2[j] = tanhf(a);
        }
        for (int j = 0; j < 15; ++j) {
            float a = bp3[j];
            for (int k = 0; k < 15; ++k) a += h2[k] * Wp3[k * 15 + j];
            h[j] = tanhf(a);
        }
        float ph[4];
        for (int j = 0; j < 4; ++j) {
            float a = bp4[j];
            for (int k = 0; k < 15; ++k) a += h[k] * Wp4[k * 4 + j];
            ph[j] = a;
        }
        const float s = ph[0] + ph[1] * sinf(0.5f * th) + ph[2] * sth
                      + ph[3] * sinf(1.5f * th);
        g_stab[g] = s;
    }

    // ---------- w-MLP weight packing (block 0 only) ----------
    if (blockIdx.x == 0) {
        for (int e = t; e < 450; e += 256) {
            int kk = e / 30, j = e % 30;
            half2_t h2v, h3v;
            h2v.x = (_Float16)(c * Ww2[(2 * kk) * 30 + j]);
            h2v.y = (_Float16)(c * Ww2[(2 * kk + 1) * 30 + j]);
            h3v.x = (_Float16)(c * Ww3[(2 * kk) * 30 + j]);
            h3v.y = (_Float16)(c * Ww3[(2 * kk + 1) * 30 + j]);
            g_w2p[e] = h2v;
            g_w3p[e] = h3v;
        }
        for (int e = t; e < 120; e += 256) {
            int kk4 = e / 8, j4 = e % 8;
            half2_t h4;
            h4.x = (_Float16)Ww4[(2 * kk4) * 8 + j4];
            h4.y = (_Float16)Ww4[(2 * kk4 + 1) * 8 + j4];
            g_w4p[e] = h4;
        }
        if (t < 60) g_w1s[t] = c * Ww1[t];
        if (t < 30) {
            g_b1s[t] = c * bw1[t];
            g_b2s[t] = c * bw2[t];
            g_b3s[t] = c * bw3[t];
        }
    }
}

// 2 points per thread; 30-wide layers processed in j-halves (16+14).
// s(theta) table staged in LDS as {s, ds} pairs -> one ds_read_b64 + fma lerp.
// waves_per_eu(4,4): pin allocator at 128-VGPR budget (round-6 showed the
// default target of 8 waves/EU spills ~50 B/thread -> +37 MB HBM traffic).
__global__ __launch_bounds__(256)
__attribute__((amdgpu_waves_per_eu(4, 4)))
void interior_kernel(
    const float4* __restrict__ x,      // two points per float4
    const float*  __restrict__ imv,
    const float*  __restrict__ lmbd,
    const float*  __restrict__ bw4,
    float* __restrict__ out, int n2)   // n2 = n/2
{
    __shared__ float2 s_tab[TABN + 1];   // 16.4 KB
    for (int i = threadIdx.x; i <= TABN; i += 256) {
        const float a = g_stab[i];
        const float b = (i < TABN) ? g_stab[i + 1] : a;
        float2 e; e.x = a; e.y = b - a;
        s_tab[i] = e;
    }
    __syncthreads();

    const int idx = blockIdx.x * blockDim.x + threadIdx.x;
    if (idx >= n2) return;

    const float4 xx = x[idx];
    const float X0[2] = {xx.x, xx.z};
    const float X1[2] = {xx.y, xx.w};

    // ========== w-MLP layer 1 (f32, prescaled): 2 -> 30, tanh, pack ==========
    half2_t apk[2][15];
    #pragma unroll
    for (int jj = 0; jj < 15; ++jj) {
        const int j0 = 2 * jj, j1 = 2 * jj + 1;
        const float wa0 = g_w1s[j0], wb0 = g_w1s[30 + j0], bb0 = g_b1s[j0];
        const float wa1 = g_w1s[j1], wb1 = g_w1s[30 + j1], bb1 = g_b1s[j1];
        #pragma unroll
        for (int p = 0; p < 2; ++p) {
            const float t0 = tanh_pre(fmaf(X1[p], wb0, fmaf(X0[p], wa0, bb0)));
            const float t1 = tanh_pre(fmaf(X1[p], wb1, fmaf(X0[p], wa1, bb1)));
            apk[p][jj] = pkrtz(t0, t1);
        }
    }

    // ========== layers 2 and 3 (fp16 dot2, f32 accum), j-halved ==========
    half2_t bpk[2][15];
    #pragma unroll
    for (int layer = 0; layer < 2; ++layer) {
        const half2_t* __restrict__ W = layer ? g_w3p : g_w2p;
        const float*   __restrict__ B = layer ? g_b3s : g_b2s;

        // ---- half 0: j = 0..15 ----
        {
            float a16[2][16];
            #pragma unroll
            for (int j = 0; j < 16; ++j) {
                const float bb = B[j];
                a16[0][j] = bb; a16[1][j] = bb;
            }
            #pragma unroll
            for (int kk = 0; kk < 15; ++kk) {
                #pragma unroll
                for (int j = 0; j < 16; ++j) {
                    const half2_t w = W[kk * 30 + j];
                    a16[0][j] = fdot2(apk[0][kk], w, a16[0][j]);
                    a16[1][j] = fdot2(apk[1][kk], w, a16[1][j]);
                }
            }
            #pragma unroll
            for (int p = 0; p < 2; ++p)
                #pragma unroll
                for (int jj = 0; jj < 8; ++jj)
                    bpk[p][jj] = pkrtz(tanh_pre(a16[p][2 * jj]),
                                       tanh_pre(a16[p][2 * jj + 1]));
        }
        // ---- half 1: j = 16..29 ----
        {
            float a14[2][14];
            #pragma unroll
            for (int j = 0; j < 14; ++j) {
                const float bb = B[16 + j];
                a14[0][j] = bb; a14[1][j] = bb;
            }
            #pragma unroll
            for (int kk = 0; kk < 15; ++kk) {
                #pragma unroll
                for (int j = 0; j < 14; ++j) {
                    const half2_t w = W[kk * 30 + 16 + j];
                    a14[0][j] = fdot2(apk[0][kk], w, a14[0][j]);
                    a14[1][j] = fdot2(apk[1][kk], w, a14[1][j]);
                }
            }
            #pragma unroll
            for (int p = 0; p < 2; ++p)
                #pragma unroll
                for (int jj = 0; jj < 7; ++jj)
                    bpk[p][8 + jj] = pkrtz(tanh_pre(a14[p][2 * jj]),
                                           tanh_pre(a14[p][2 * jj + 1]));
        }
        // feed next layer
        #pragma unroll
        for (int p = 0; p < 2; ++p)
            #pragma unroll
            for (int kk = 0; kk < 15; ++kk)
                apk[p][kk] = bpk[p][kk];
    }

    // ========== layer 4 (fp16 dot2, unscaled): 30 -> 8 ==========
    float wv[2][8];
    #pragma unroll
    for (int j = 0; j < 8; ++j) {
        const float bb = bw4[j];
        wv[0][j] = bb; wv[1][j] = bb;
    }
    #pragma unroll
    for (int kk = 0; kk < 15; ++kk) {
        #pragma unroll
        for (int j = 0; j < 8; ++j) {
            const half2_t w = g_w4p[kk * 8 + j];
            wv[0][j] = fdot2(apk[0][kk], w, wv[0][j]);
            wv[1][j] = fdot2(apk[1][kk], w, wv[1][j]);
        }
    }

    // Fence: keep the epilogue (incl. its LDS gathers) from being hoisted
    // into / above the unrolled MLP region (round-6 spill pathology).
    __builtin_amdgcn_sched_barrier(0);

    // ========== geometry + phi-table + singular + combine ==========
    const float im0 = imv[0], im1 = imv[1], lam = lmbd[0];
    float res[2];
    #pragma unroll
    for (int p = 0; p < 2; ++p) {
        const float x0 = X0[p], x1 = X1[p];
        const float dx = x0 - im0, dy = x1 - im1;
        const float r  = sqrtf(fmaf(dx, dx, dy * dy));

        // yita(r)
        const float t  = fminf(fmaxf(fmaf(2.5f, r, -1.25f), 0.0f), 1.0f);
        const float t3 = t * t * t;
        const float yv = fmaf(fmaf(fmaf(-6.0f, t, 15.0f), t, -10.0f), t3, 1.0f);

        // r^lambda (sqrt fast path for lambda == 0.5)
        float rl;
        if (lam == 0.5f) rl = sqrtf(r);
        else rl = __builtin_amdgcn_exp2f(lam * __builtin_amdgcn_logf(fmaxf(r, 1e-20f)));

        // diamond-angle parameter p(theta) in [-2,2], no trig
        const float l1n = fmaxf(fabsf(dx) + fabsf(dy), 1e-20f);
        const float u   = dy * __builtin_amdgcn_rcpf(l1n);
        const float pbk = (dy >= 0.0f) ? (2.0f - u) : (-2.0f - u);
        const float pth = (dx >= 0.0f) ? u : pbk;

        // LDS table lerp: s(theta)
        const float fi = fminf(fmaxf(fmaf(pth, (float)(TABN / 4), (float)(TABN / 2)),
                                     0.0f), (float)TABN - 0.001f);
        const int   ii = (int)fi;
        const float fr = fi - (float)ii;
        const float2 sd = s_tab[ii];
        const float sval = fmaf(fr, sd.y, sd.x);

        // singular functions at x (about origin), algebraically reduced:
        // vp0 = r0^0.5 sin(th/2) = copysign(sqrt((r0-x0)/2), x1)
        // vp1 = x1
        // vp2 = r0^1.5 sin(1.5 th) = x1*sqrt((r0+x0)/2) + x0*vp0
        const float r0 = sqrtf(fmaf(x0, x0, x1 * x1));
        const float A  = sqrtf(fmaxf(0.0f, (r0 - x0) * 0.5f));
        const float Bq = sqrtf(fmaxf(0.0f, (r0 + x0) * 0.5f));
        const float vp0 = copysignf(A, x1);
        const float vp2 = fmaf(x1, Bq, x0 * vp0);

        float rp = fmaf(yv, wv[p][4], wv[p][0]);
        rp = fmaf(fmaf(wv[p][5], yv, wv[p][1]), vp0, rp);
        rp = fmaf(fmaf(wv[p][6], yv, wv[p][2]), x1, rp);
        rp = fmaf(fmaf(wv[p][7], yv, wv[p][3]), vp2, rp);

        res[p] = fmaf(sval * yv, rl, rp);
    }

    // contiguous pair store
    float2 o; o.x = res[0]; o.y = res[1];
    ((float2*)out)[idx] = o;
}

extern "C" void kernel_launch(void* const* d_in, const int* in_sizes, int n_in,
                              void* d_out, int out_size, void* d_ws, size_t ws_size,
                              hipStream_t stream) {
    const float4* x   = (const float4*)d_in[0];
    const float* imv  = (const float*)d_in[1];
    const float* lmbd = (const float*)d_in[2];
    const float* Ww1  = (const float*)d_in[3];
    const float* bw1  = (const float*)d_in[4];
    const float* Ww2  = (const float*)d_in[5];
    const float* bw2  = (const float*)d_in[6];
    const float* Ww3  = (const float*)d_in[7];
    const float* bw3  = (const float*)d_in[8];
    const float* Ww4  = (const float*)d_in[9];
    const float* bw4  = (const float*)d_in[10];
    const float* Wp1  = (const float*)d_in[11];
    const float* bp1  = (const float*)d_in[12];
    const float* Wp2  = (const float*)d_in[13];
    const float* bp2  = (const float*)d_in[14];
    const float* Wp3  = (const float*)d_in[15];
    const float* bp3  = (const float*)d_in[16];
    const float* Wp4  = (const float*)d_in[17];
    const float* bp4  = (const float*)d_in[18];
    float* out = (float*)d_out;

    const int n  = in_sizes[0] / 2;
    const int n2 = n / 2;

    // 9 blocks cover TABN+1 = 2049 table entries; block 0 also packs weights.
    prep_kernel<<<9, 256, 0, stream>>>(Ww1, bw1, Ww2, bw2, Ww3, bw3, Ww4,
                                       Wp1, bp1, Wp2, bp2, Wp3, bp3, Wp4, bp4);

    const int block = 256;
    const int grid = (n2 + block - 1) / block;
    interior_kernel<<<grid, block, 0, stream>>>(
        x, imv, lmbd, bw4, out, n2);
}

// Round 8
// 174.048 us; speedup vs baseline: 1.4601x; 1.4555x over previous
//
#include <hip/hip_runtime.h>
#include <math.h>

typedef _Float16 half2_t __attribute__((ext_vector_type(2)));

#define CEXP 2.8853900817779268f  // 2*log2(e): tanh(z) = 1 - 2/(2^(c*z)+1)
#define TABN 2048                 // s(theta) table cells

// Prepped-weight storage (rewritten by prep_kernel on every launch).
// w-MLP matrices stored [kk][j] so the unrolled j-inner loop reads consecutive
// dwords. phi-MLP is folded into the 1-D s(theta) table g_stab2 = {s, ds}.
__device__ float   g_w1s[60];    // c*Ww1  [2][30]
__device__ float   g_b1s[30];    // c*bw1
__device__ half2_t g_w2p[450];   // [kk=15][j=30]: {c*W2[2kk][j], c*W2[2kk+1][j]}
__device__ float   g_b2s[30];
__device__ half2_t g_w3p[450];   // [kk=15][j=30]
__device__ float   g_b3s[30];
__device__ half2_t g_w4p[120];   // [kk=15][j=8] (unscaled)
__device__ float2  g_stab2[TABN];  // cell i: {s(p_i), s(p_{i+1}) - s(p_i)}

static __device__ __forceinline__ float fdot2(half2_t a, half2_t b, float c) {
#if __has_builtin(__builtin_amdgcn_fdot2)
    return __builtin_amdgcn_fdot2(a, b, c, false);
#else
    return fmaf((float)a.x, (float)b.x, fmaf((float)a.y, (float)b.y, c));
#endif
}

static __device__ __forceinline__ half2_t pkrtz(float a, float b) {
    return __builtin_bit_cast(half2_t, __builtin_amdgcn_cvt_pkrtz(a, b));
}

// tanh with the 2*log2(e) factor pre-folded into the incoming accumulator.
static __device__ __forceinline__ float tanh_pre(float z) {
    float e = __builtin_amdgcn_exp2f(z);
    float r = __builtin_amdgcn_rcpf(e + 1.0f);
    return fmaf(-2.0f, r, 1.0f);
}

// Full phi-branch value s(theta(p)) at diamond-angle parameter p in [-2,2].
static __device__ float s_of_p(float pth,
    const float* __restrict__ Wp1, const float* __restrict__ bp1,
    const float* __restrict__ Wp2, const float* __restrict__ bp2,
    const float* __restrict__ Wp3, const float* __restrict__ bp3,
    const float* __restrict__ Wp4, const float* __restrict__ bp4)
{
    float th;
    if (pth >= -1.0f && pth <= 1.0f) {
        th = atanf(pth / (1.0f - fabsf(pth)));      // /0 -> inf -> atan=pi/2 ok
    } else if (pth > 1.0f) {
        const float uu = 2.0f - pth;                // [0,1)
        th = (float)M_PI - atanf(uu / (1.0f - uu));
    } else {
        const float uu = -2.0f - pth;               // (-1,0]
        th = -(float)M_PI + atanf(-uu / (1.0f + uu));
    }
    const float cth = cosf(th), sth = sinf(th);

    // phi-MLP in f32 with exact tanh: 2 -> 15 -> 15 -> 15 -> 4
    float h[15], h2[15];
    for (int j = 0; j < 15; ++j)
        h[j] = tanhf(cth * Wp1[j] + sth * Wp1[15 + j] + bp1[j]);
    for (int j = 0; j < 15; ++j) {
        float a = bp2[j];
        for (int k = 0; k < 15; ++k) a += h[k] * Wp2[k * 15 + j];
        h2[j] = tanhf(a);
    }
    for (int j = 0; j < 15; ++j) {
        float a = bp3[j];
        for (int k = 0; k < 15; ++k) a += h2[k] * Wp3[k * 15 + j];
        h[j] = tanhf(a);
    }
    float ph[4];
    for (int j = 0; j < 4; ++j) {
        float a = bp4[j];
        for (int k = 0; k < 15; ++k) a += h[k] * Wp4[k * 4 + j];
        ph[j] = a;
    }
    return ph[0] + ph[1] * sinf(0.5f * th) + ph[2] * sth + ph[3] * sinf(1.5f * th);
}

// 8 blocks x 256 threads = 2048 table cells; block 0 also packs w-weights.
__global__ __launch_bounds__(256) void prep_kernel(
    const float* __restrict__ Ww1, const float* __restrict__ bw1,
    const float* __restrict__ Ww2, const float* __restrict__ bw2,
    const float* __restrict__ Ww3, const float* __restrict__ bw3,
    const float* __restrict__ Ww4,
    const float* __restrict__ Wp1, const float* __restrict__ bp1,
    const float* __restrict__ Wp2, const float* __restrict__ bp2,
    const float* __restrict__ Wp3, const float* __restrict__ bp3,
    const float* __restrict__ Wp4, const float* __restrict__ bp4)
{
    const int t = threadIdx.x;
    const int g = blockIdx.x * 256 + t;
    const float c = CEXP;

    if (g < TABN) {
        const float h  = 4.0f / (float)TABN;
        const float p0 = -2.0f + h * (float)g;
        const float s0 = s_of_p(p0,     Wp1, bp1, Wp2, bp2, Wp3, bp3, Wp4, bp4);
        const float s1 = s_of_p(p0 + h, Wp1, bp1, Wp2, bp2, Wp3, bp3, Wp4, bp4);
        float2 e; e.x = s0; e.y = s1 - s0;
        g_stab2[g] = e;
    }

    if (blockIdx.x == 0) {
        for (int e = t; e < 450; e += 256) {
            int kk = e / 30, j = e % 30;
            half2_t h2v, h3v;
            h2v.x = (_Float16)(c * Ww2[(2 * kk) * 30 + j]);
            h2v.y = (_Float16)(c * Ww2[(2 * kk + 1) * 30 + j]);
            h3v.x = (_Float16)(c * Ww3[(2 * kk) * 30 + j]);
            h3v.y = (_Float16)(c * Ww3[(2 * kk + 1) * 30 + j]);
            g_w2p[e] = h2v;
            g_w3p[e] = h3v;
        }
        for (int e = t; e < 120; e += 256) {
            int kk4 = e / 8, j4 = e % 8;
            half2_t h4;
            h4.x = (_Float16)Ww4[(2 * kk4) * 8 + j4];
            h4.y = (_Float16)Ww4[(2 * kk4 + 1) * 8 + j4];
            g_w4p[e] = h4;
        }
        if (t < 60) g_w1s[t] = c * Ww1[t];
        if (t < 30) {
            g_b1s[t] = c * bw1[t];
            g_b2s[t] = c * bw2[t];
            g_b3s[t] = c * bw3[t];
        }
    }
}

// 2 points per thread. ORDERING: epilogue-precompute FIRST (pressure ~10 regs,
// table gather latency hidden under the MLP), then the round-5 MLP structure
// (44-VGPR proven), then a pure-fma combine. Round 6/7 had the epilogue after
// the MLP and the junction's combined live set spilled ~20 regs/thread
// (+40 MB HBM write traffic).
__global__ __launch_bounds__(256, 4) void interior_kernel(
    const float4* __restrict__ x,      // two points per float4
    const float*  __restrict__ imv,
    const float*  __restrict__ lmbd,
    const float*  __restrict__ bw4,
    float* __restrict__ out, int n2)   // n2 = n/2
{
    const int idx = blockIdx.x * blockDim.x + threadIdx.x;
    if (idx >= n2) return;

    const float4 xx = x[idx];
    const float X0[2] = {xx.x, xx.z};
    const float X1[2] = {xx.y, xx.w};

    // ===== epilogue precompute: 4 carried scalars per point =====
    const float im0 = imv[0], im1 = imv[1], lam = lmbd[0];
    float YVc[2], VP0c[2], VP2c[2], SRLc[2];
    #pragma unroll
    for (int p = 0; p < 2; ++p) {
        const float x0 = X0[p], x1 = X1[p];
        const float dx = x0 - im0, dy = x1 - im1;
        const float r  = sqrtf(fmaf(dx, dx, dy * dy));

        // yita(r)
        const float t  = fminf(fmaxf(fmaf(2.5f, r, -1.25f), 0.0f), 1.0f);
        const float t3 = t * t * t;
        const float yv = fmaf(fmaf(fmaf(-6.0f, t, 15.0f), t, -10.0f), t3, 1.0f);

        // r^lambda (sqrt fast path for lambda == 0.5)
        float rl;
        if (lam == 0.5f) rl = sqrtf(r);
        else rl = __builtin_amdgcn_exp2f(lam * __builtin_amdgcn_logf(fmaxf(r, 1e-20f)));

        // diamond-angle parameter p(theta) in [-2,2], no trig
        const float l1n = fmaxf(fabsf(dx) + fabsf(dy), 1e-20f);
        const float u   = dy * __builtin_amdgcn_rcpf(l1n);
        const float pbk = (dy >= 0.0f) ? (2.0f - u) : (-2.0f - u);
        const float pth = (dx >= 0.0f) ? u : pbk;

        // table gather: cell {s, ds}, one 8 B load
        const float fi = fminf(fmaxf(fmaf(pth, (float)(TABN / 4), (float)(TABN / 2)),
                                     0.0f), (float)TABN - 0.001f);
        const int   ii = (int)fi;
        const float fr = fi - (float)ii;
        const float2 sd = g_stab2[ii];
        const float sval = fmaf(fr, sd.y, sd.x);

        // singular functions at x (about origin), algebraically reduced:
        // vp0 = r0^0.5 sin(th/2) = copysign(sqrt((r0-x0)/2), x1)
        // vp2 = r0^1.5 sin(1.5 th) = x1*sqrt((r0+x0)/2) + x0*vp0
        const float r0 = sqrtf(fmaf(x0, x0, x1 * x1));
        const float A  = sqrtf(fmaxf(0.0f, (r0 - x0) * 0.5f));
        const float Bq = sqrtf(fmaxf(0.0f, (r0 + x0) * 0.5f));
        const float vp0 = copysignf(A, x1);

        YVc[p]  = yv;
        VP0c[p] = vp0;
        VP2c[p] = fmaf(x1, Bq, x0 * vp0);
        SRLc[p] = sval * yv * rl;
    }

    // Pin: precompute stays above the MLP (this order is pressure-optimal).
    __builtin_amdgcn_sched_barrier(0);

    // ========== w-MLP layer 1 (f32, prescaled): 2 -> 30, tanh, pack ==========
    half2_t apk[2][15];
    #pragma unroll
    for (int jj = 0; jj < 15; ++jj) {
        const int j0 = 2 * jj, j1 = 2 * jj + 1;
        const float wa0 = g_w1s[j0], wb0 = g_w1s[30 + j0], bb0 = g_b1s[j0];
        const float wa1 = g_w1s[j1], wb1 = g_w1s[30 + j1], bb1 = g_b1s[j1];
        #pragma unroll
        for (int p = 0; p < 2; ++p) {
            const float t0 = tanh_pre(fmaf(X1[p], wb0, fmaf(X0[p], wa0, bb0)));
            const float t1 = tanh_pre(fmaf(X1[p], wb1, fmaf(X0[p], wa1, bb1)));
            apk[p][jj] = pkrtz(t0, t1);
        }
    }

    // ========== layers 2 and 3 (fp16 dot2, f32 accum), j-halved ==========
    half2_t bpk[2][15];
    #pragma unroll
    for (int layer = 0; layer < 2; ++layer) {
        const half2_t* __restrict__ W = layer ? g_w3p : g_w2p;
        const float*   __restrict__ B = layer ? g_b3s : g_b2s;

        // ---- half 0: j = 0..15 ----
        {
            float a16[2][16];
            #pragma unroll
            for (int j = 0; j < 16; ++j) {
                const float bb = B[j];
                a16[0][j] = bb; a16[1][j] = bb;
            }
            #pragma unroll
            for (int kk = 0; kk < 15; ++kk) {
                #pragma unroll
                for (int j = 0; j < 16; ++j) {
                    const half2_t w = W[kk * 30 + j];
                    a16[0][j] = fdot2(apk[0][kk], w, a16[0][j]);
                    a16[1][j] = fdot2(apk[1][kk], w, a16[1][j]);
                }
            }
            #pragma unroll
            for (int p = 0; p < 2; ++p)
                #pragma unroll
                for (int jj = 0; jj < 8; ++jj)
                    bpk[p][jj] = pkrtz(tanh_pre(a16[p][2 * jj]),
                                       tanh_pre(a16[p][2 * jj + 1]));
        }
        // ---- half 1: j = 16..29 ----
        {
            float a14[2][14];
            #pragma unroll
            for (int j = 0; j < 14; ++j) {
                const float bb = B[16 + j];
                a14[0][j] = bb; a14[1][j] = bb;
            }
            #pragma unroll
            for (int kk = 0; kk < 15; ++kk) {
                #pragma unroll
                for (int j = 0; j < 14; ++j) {
                    const half2_t w = W[kk * 30 + 16 + j];
                    a14[0][j] = fdot2(apk[0][kk], w, a14[0][j]);
                    a14[1][j] = fdot2(apk[1][kk], w, a14[1][j]);
                }
            }
            #pragma unroll
            for (int p = 0; p < 2; ++p)
                #pragma unroll
                for (int jj = 0; jj < 7; ++jj)
                    bpk[p][8 + jj] = pkrtz(tanh_pre(a14[p][2 * jj]),
                                           tanh_pre(a14[p][2 * jj + 1]));
        }
        // feed next layer
        #pragma unroll
        for (int p = 0; p < 2; ++p)
            #pragma unroll
            for (int kk = 0; kk < 15; ++kk)
                apk[p][kk] = bpk[p][kk];
    }

    // ========== layer 4 (fp16 dot2, unscaled): 30 -> 8 ==========
    float wv[2][8];
    #pragma unroll
    for (int j = 0; j < 8; ++j) {
        const float bb = bw4[j];
        wv[0][j] = bb; wv[1][j] = bb;
    }
    #pragma unroll
    for (int kk = 0; kk < 15; ++kk) {
        #pragma unroll
        for (int j = 0; j < 8; ++j) {
            const half2_t w = g_w4p[kk * 8 + j];
            wv[0][j] = fdot2(apk[0][kk], w, wv[0][j]);
            wv[1][j] = fdot2(apk[1][kk], w, wv[1][j]);
        }
    }

    // ========== combine (pure fma) ==========
    float res[2];
    #pragma unroll
    for (int p = 0; p < 2; ++p) {
        const float yv = YVc[p];
        float rp = fmaf(yv, wv[p][4], wv[p][0]);
        rp = fmaf(fmaf(wv[p][5], yv, wv[p][1]), VP0c[p], rp);
        rp = fmaf(fmaf(wv[p][6], yv, wv[p][2]), X1[p], rp);
        rp = fmaf(fmaf(wv[p][7], yv, wv[p][3]), VP2c[p], rp);
        res[p] = rp + SRLc[p];
    }

    float2 o; o.x = res[0]; o.y = res[1];
    ((float2*)out)[idx] = o;
}

extern "C" void kernel_launch(void* const* d_in, const int* in_sizes, int n_in,
                              void* d_out, int out_size, void* d_ws, size_t ws_size,
                              hipStream_t stream) {
    const float4* x   = (const float4*)d_in[0];
    const float* imv  = (const float*)d_in[1];
    const float* lmbd = (const float*)d_in[2];
    const float* Ww1  = (const float*)d_in[3];
    const float* bw1  = (const float*)d_in[4];
    const float* Ww2  = (const float*)d_in[5];
    const float* bw2  = (const float*)d_in[6];
    const float* Ww3  = (const float*)d_in[7];
    const float* bw3  = (const float*)d_in[8];
    const float* Ww4  = (const float*)d_in[9];
    const float* bw4  = (const float*)d_in[10];
    const float* Wp1  = (const float*)d_in[11];
    const float* bp1  = (const float*)d_in[12];
    const float* Wp2  = (const float*)d_in[13];
    const float* bp2  = (const float*)d_in[14];
    const float* Wp3  = (const float*)d_in[15];
    const float* bp3  = (const float*)d_in[16];
    const float* Wp4  = (const float*)d_in[17];
    const float* bp4  = (const float*)d_in[18];
    float* out = (float*)d_out;

    const int n  = in_sizes[0] / 2;
    const int n2 = n / 2;

    // 8 blocks cover TABN = 2048 table cells; block 0 also packs weights.
    prep_kernel<<<8, 256, 0, stream>>>(Ww1, bw1, Ww2, bw2, Ww3, bw3, Ww4,
                                       Wp1, bp1, Wp2, bp2, Wp3, bp3, Wp4, bp4);

    const int block = 256;
    const int grid = (n2 + block - 1) / block;
    interior_kernel<<<grid, block, 0, stream>>>(
        x, imv, lmbd, bw4, out, n2);
}

// Round 9
// 156.855 us; speedup vs baseline: 1.6201x; 1.1096x over previous
//
#include <hip/hip_runtime.h>
#include <math.h>

#define TABN 2048   // s(theta) table cells
#define NC   320    // w(x) grid cells per axis
#define NN   321    // w(x) grid nodes per axis

// Tables (rewritten by prep_kernel on every launch; kernel-boundary release
// makes them visible to interior_kernel across XCDs).
__device__ float  g_wtab[NN * NN * 8];  // [iy][ix][8] = w-MLP outputs, 3.3 MB
__device__ float2 g_stab2[TABN];        // cell i: {s(p_i), s(p_{i+1}) - s(p_i)}

// Full phi-branch value s(theta(p)) at diamond-angle parameter p in [-2,2].
static __device__ float s_of_p(float pth,
    const float* __restrict__ Wp1, const float* __restrict__ bp1,
    const float* __restrict__ Wp2, const float* __restrict__ bp2,
    const float* __restrict__ Wp3, const float* __restrict__ bp3,
    const float* __restrict__ Wp4, const float* __restrict__ bp4)
{
    float th;
    if (pth >= -1.0f && pth <= 1.0f) {
        th = atanf(pth / (1.0f - fabsf(pth)));      // /0 -> inf -> atan=pi/2 ok
    } else if (pth > 1.0f) {
        const float uu = 2.0f - pth;                // [0,1)
        th = (float)M_PI - atanf(uu / (1.0f - uu));
    } else {
        const float uu = -2.0f - pth;               // (-1,0]
        th = -(float)M_PI + atanf(-uu / (1.0f + uu));
    }
    const float cth = cosf(th), sth = sinf(th);

    // phi-MLP in f32 with exact tanh: 2 -> 15 -> 15 -> 15 -> 4
    float h[15], h2[15];
    for (int j = 0; j < 15; ++j)
        h[j] = tanhf(cth * Wp1[j] + sth * Wp1[15 + j] + bp1[j]);
    for (int j = 0; j < 15; ++j) {
        float a = bp2[j];
        for (int k = 0; k < 15; ++k) a += h[k] * Wp2[k * 15 + j];
        h2[j] = tanhf(a);
    }
    for (int j = 0; j < 15; ++j) {
        float a = bp3[j];
        for (int k = 0; k < 15; ++k) a += h2[k] * Wp3[k * 15 + j];
        h[j] = tanhf(a);
    }
    float ph[4];
    for (int j = 0; j < 4; ++j) {
        float a = bp4[j];
        for (int k = 0; k < 15; ++k) a += h[k] * Wp4[k * 4 + j];
        ph[j] = a;
    }
    return ph[0] + ph[1] * sinf(0.5f * th) + ph[2] * sth + ph[3] * sinf(1.5f * th);
}

// gid < NN*NN: one w(x)-grid node (full f32 w-MLP).
// else: one s(theta) table cell.
__global__ __launch_bounds__(256) void prep_kernel(
    const float* __restrict__ Ww1, const float* __restrict__ bw1,
    const float* __restrict__ Ww2, const float* __restrict__ bw2,
    const float* __restrict__ Ww3, const float* __restrict__ bw3,
    const float* __restrict__ Ww4, const float* __restrict__ bw4,
    const float* __restrict__ Wp1, const float* __restrict__ bp1,
    const float* __restrict__ Wp2, const float* __restrict__ bp2,
    const float* __restrict__ Wp3, const float* __restrict__ bp3,
    const float* __restrict__ Wp4, const float* __restrict__ bp4)
{
    const int gid = blockIdx.x * 256 + threadIdx.x;

    if (gid < NN * NN) {
        const int ix = gid % NN, iy = gid / NN;
        const float x0 = (float)ix * (1.0f / (float)NC);
        const float x1 = (float)iy * (1.0f / (float)NC);

        float h1[30], h2[30];
        for (int j = 0; j < 30; ++j)
            h1[j] = tanhf(x0 * Ww1[j] + x1 * Ww1[30 + j] + bw1[j]);
        for (int j = 0; j < 30; ++j) {
            float a = bw2[j];
            for (int k = 0; k < 30; ++k) a += h1[k] * Ww2[k * 30 + j];
            h2[j] = tanhf(a);
        }
        for (int j = 0; j < 30; ++j) {
            float a = bw3[j];
            for (int k = 0; k < 30; ++k) a += h2[k] * Ww3[k * 30 + j];
            h1[j] = tanhf(a);
        }
        for (int j = 0; j < 8; ++j) {
            float a = bw4[j];
            for (int k = 0; k < 30; ++k) a += h1[k] * Ww4[k * 8 + j];
            g_wtab[gid * 8 + j] = a;
        }
        return;
    }

    const int cell = gid - NN * NN;
    if (cell < TABN) {
        const float h  = 4.0f / (float)TABN;
        const float p0 = -2.0f + h * (float)cell;
        const float s0 = s_of_p(p0,     Wp1, bp1, Wp2, bp2, Wp3, bp3, Wp4, bp4);
        const float s1 = s_of_p(p0 + h, Wp1, bp1, Wp2, bp2, Wp3, bp3, Wp4, bp4);
        float2 e; e.x = s0; e.y = s1 - s0;
        g_stab2[cell] = e;
    }
}

// 2 points per thread. Entire per-point compute is table gathers + ~90 VALU
// ops: bilinear w(x) from the 2-D grid (L2-resident), s(theta) from the 1-D
// table, plus the closed-form geometry/singular-function epilogue.
__global__ __launch_bounds__(256) void interior_kernel(
    const float4* __restrict__ x,      // two points per float4
    const float*  __restrict__ imv,
    const float*  __restrict__ lmbd,
    float* __restrict__ out, int n2)   // n2 = n/2
{
    const int idx = blockIdx.x * blockDim.x + threadIdx.x;
    if (idx >= n2) return;

    const float4 xx = x[idx];
    const float X0[2] = {xx.x, xx.z};
    const float X1[2] = {xx.y, xx.w};
    const float im0 = imv[0], im1 = imv[1], lam = lmbd[0];

    const float4* __restrict__ T = (const float4*)g_wtab;

    float res[2];
    #pragma unroll
    for (int p = 0; p < 2; ++p) {
        const float x0 = X0[p], x1 = X1[p];

        // ---- bilinear gather of w[0..8) from the 2-D grid ----
        const float fx = x0 * (float)NC;
        const float fy = x1 * (float)NC;
        int ix = (int)fx; ix = ix < 0 ? 0 : (ix > NC - 1 ? NC - 1 : ix);
        int iy = (int)fy; iy = iy < 0 ? 0 : (iy > NC - 1 ? NC - 1 : iy);
        const float frx = fx - (float)ix;
        const float fry = fy - (float)iy;

        const int k = (iy * NN + ix) * 2;        // float4 units
        const float4 a0 = T[k],            a1 = T[k + 1];          // (ix  ,iy)
        const float4 b0 = T[k + 2],        b1 = T[k + 3];          // (ix+1,iy)
        const float4 c0 = T[k + NN * 2],   c1 = T[k + NN * 2 + 1]; // (ix  ,iy+1)
        const float4 d0 = T[k + NN * 2 + 2], d1 = T[k + NN * 2 + 3];

        float wv[8];
        {
            const float* A = (const float*)&a0;  // a0,a1 contiguous? not in reg;
            // do it component-wise to stay in registers:
        }
        {
            const float A[8] = {a0.x, a0.y, a0.z, a0.w, a1.x, a1.y, a1.z, a1.w};
            const float B[8] = {b0.x, b0.y, b0.z, b0.w, b1.x, b1.y, b1.z, b1.w};
            const float C[8] = {c0.x, c0.y, c0.z, c0.w, c1.x, c1.y, c1.z, c1.w};
            const float D[8] = {d0.x, d0.y, d0.z, d0.w, d1.x, d1.y, d1.z, d1.w};
            #pragma unroll
            for (int j = 0; j < 8; ++j) {
                const float r0 = fmaf(frx, B[j] - A[j], A[j]);
                const float r1 = fmaf(frx, D[j] - C[j], C[j]);
                wv[j] = fmaf(fry, r1 - r0, r0);
            }
        }

        // ---- geometry about the interior vertex ----
        const float dx = x0 - im0, dy = x1 - im1;
        const float r  = sqrtf(fmaf(dx, dx, dy * dy));

        // yita(r)
        const float t  = fminf(fmaxf(fmaf(2.5f, r, -1.25f), 0.0f), 1.0f);
        const float t3 = t * t * t;
        const float yv = fmaf(fmaf(fmaf(-6.0f, t, 15.0f), t, -10.0f), t3, 1.0f);

        // r^lambda (sqrt fast path for lambda == 0.5)
        float rl;
        if (lam == 0.5f) rl = sqrtf(r);
        else rl = __builtin_amdgcn_exp2f(lam * __builtin_amdgcn_logf(fmaxf(r, 1e-20f)));

        // diamond-angle parameter p(theta) in [-2,2], no trig
        const float l1n = fmaxf(fabsf(dx) + fabsf(dy), 1e-20f);
        const float u   = dy * __builtin_amdgcn_rcpf(l1n);
        const float pbk = (dy >= 0.0f) ? (2.0f - u) : (-2.0f - u);
        const float pth = (dx >= 0.0f) ? u : pbk;

        // s(theta) table gather: cell {s, ds}, one 8 B load
        const float fi = fminf(fmaxf(fmaf(pth, (float)(TABN / 4), (float)(TABN / 2)),
                                     0.0f), (float)TABN - 0.001f);
        const int   ii = (int)fi;
        const float fr = fi - (float)ii;
        const float2 sd = g_stab2[ii];
        const float sval = fmaf(fr, sd.y, sd.x);

        // singular functions at x (about origin), algebraically reduced:
        // vp0 = r0^0.5 sin(th/2) = copysign(sqrt((r0-x0)/2), x1)
        // vp1 = x1
        // vp2 = r0^1.5 sin(1.5 th) = x1*sqrt((r0+x0)/2) + x0*vp0
        const float r0 = sqrtf(fmaf(x0, x0, x1 * x1));
        const float A  = sqrtf(fmaxf(0.0f, (r0 - x0) * 0.5f));
        const float Bq = sqrtf(fmaxf(0.0f, (r0 + x0) * 0.5f));
        const float vp0 = copysignf(A, x1);
        const float vp2 = fmaf(x1, Bq, x0 * vp0);

        // combine
        float rp = fmaf(yv, wv[4], wv[0]);
        rp = fmaf(fmaf(wv[5], yv, wv[1]), vp0, rp);
        rp = fmaf(fmaf(wv[6], yv, wv[2]), x1, rp);
        rp = fmaf(fmaf(wv[7], yv, wv[3]), vp2, rp);
        res[p] = fmaf(sval * yv, rl, rp);
    }

    float2 o; o.x = res[0]; o.y = res[1];
    ((float2*)out)[idx] = o;
}

extern "C" void kernel_launch(void* const* d_in, const int* in_sizes, int n_in,
                              void* d_out, int out_size, void* d_ws, size_t ws_size,
                              hipStream_t stream) {
    const float4* x   = (const float4*)d_in[0];
    const float* imv  = (const float*)d_in[1];
    const float* lmbd = (const float*)d_in[2];
    const float* Ww1  = (const float*)d_in[3];
    const float* bw1  = (const float*)d_in[4];
    const float* Ww2  = (const float*)d_in[5];
    const float* bw2  = (const float*)d_in[6];
    const float* Ww3  = (const float*)d_in[7];
    const float* bw3  = (const float*)d_in[8];
    const float* Ww4  = (const float*)d_in[9];
    const float* bw4  = (const float*)d_in[10];
    const float* Wp1  = (const float*)d_in[11];
    const float* bp1  = (const float*)d_in[12];
    const float* Wp2  = (const float*)d_in[13];
    const float* bp2  = (const float*)d_in[14];
    const float* Wp3  = (const float*)d_in[15];
    const float* bp3  = (const float*)d_in[16];
    const float* Wp4  = (const float*)d_in[17];
    const float* bp4  = (const float*)d_in[18];
    float* out = (float*)d_out;

    const int n  = in_sizes[0] / 2;
    const int n2 = n / 2;

    // NN*NN w-grid nodes + TABN s-table cells, one thread each.
    const int prep_threads = NN * NN + TABN;
    const int prep_blocks  = (prep_threads + 255) / 256;
    prep_kernel<<<prep_blocks, 256, 0, stream>>>(
        Ww1, bw1, Ww2, bw2, Ww3, bw3, Ww4, bw4,
        Wp1, bp1, Wp2, bp2, Wp3, bp3, Wp4, bp4);

    const int block = 256;
    const int grid = (n2 + block - 1) / block;
    interior_kernel<<<grid, block, 0, stream>>>(x, imv, lmbd, out, n2);
}

// Round 10
// 140.420 us; speedup vs baseline: 1.8097x; 1.1170x over previous
//
#include <hip/hip_runtime.h>
#include <math.h>

#define CEXP 2.8853900817779268f  // 2*log2(e): tanh(z) = 1 - 2/(2^(c*z)+1)
#define TABN 2048   // s(theta) table cells
#define NC   320    // w(x) grid cells per axis
#define NN   321    // w(x) grid nodes per axis
#define WBLK ((NN * NN + 255) / 256)   // 403 blocks for the w-grid

// Tables (rewritten by prep_kernel on every launch; kernel boundary makes
// them visible to interior_kernel across XCDs).
__device__ float  g_wtab[NN * NN * 8];  // [iy][ix][8] = w-MLP outputs, 3.3 MB
__device__ float2 g_stab2[TABN];        // cell i: {s(p_i), s(p_{i+1}) - s(p_i)}

// tanh with the 2*log2(e) factor pre-folded into the incoming accumulator.
static __device__ __forceinline__ float tanh_pre(float z) {
    float e = __builtin_amdgcn_exp2f(z);
    float r = __builtin_amdgcn_rcpf(e + 1.0f);
    return fmaf(-2.0f, r, 1.0f);
}

// Full phi-branch value s(theta(p)) at diamond-angle parameter p in [-2,2].
static __device__ float s_of_p(float pth,
    const float* __restrict__ Wp1, const float* __restrict__ bp1,
    const float* __restrict__ Wp2, const float* __restrict__ bp2,
    const float* __restrict__ Wp3, const float* __restrict__ bp3,
    const float* __restrict__ Wp4, const float* __restrict__ bp4)
{
    float th;
    if (pth >= -1.0f && pth <= 1.0f) {
        th = atanf(pth / (1.0f - fabsf(pth)));      // /0 -> inf -> atan=pi/2 ok
    } else if (pth > 1.0f) {
        const float uu = 2.0f - pth;                // [0,1)
        th = (float)M_PI - atanf(uu / (1.0f - uu));
    } else {
        const float uu = -2.0f - pth;               // (-1,0]
        th = -(float)M_PI + atanf(-uu / (1.0f + uu));
    }
    const float cth = cosf(th), sth = sinf(th);

    // phi-MLP in f32 with exact tanh: 2 -> 15 -> 15 -> 15 -> 4
    float h[15], h2[15];
    for (int j = 0; j < 15; ++j)
        h[j] = tanhf(cth * Wp1[j] + sth * Wp1[15 + j] + bp1[j]);
    for (int j = 0; j < 15; ++j) {
        float a = bp2[j];
        for (int k = 0; k < 15; ++k) a += h[k] * Wp2[k * 15 + j];
        h2[j] = tanhf(a);
    }
    for (int j = 0; j < 15; ++j) {
        float a = bp3[j];
        for (int k = 0; k < 15; ++k) a += h2[k] * Wp3[k * 15 + j];
        h[j] = tanhf(a);
    }
    float ph[4];
    for (int j = 0; j < 4; ++j) {
        float a = bp4[j];
        for (int k = 0; k < 15; ++k) a += h[k] * Wp4[k * 4 + j];
        ph[j] = a;
    }
    return ph[0] + ph[1] * sinf(0.5f * th) + ph[2] * sth + ph[3] * sinf(1.5f * th);
}

// Blocks [0, WBLK): w(x)-grid nodes, weights staged in LDS (round-9's version
// was 52 us: global weight loads under a thread-divergent branch defeated
// scalarization -> latency-bound at VALUBusy 16%). Blocks [WBLK, WBLK+8):
// s(theta) table. Branch is BLOCK-uniform.
__global__ __launch_bounds__(256) void prep_kernel(
    const float* __restrict__ Ww1, const float* __restrict__ bw1,
    const float* __restrict__ Ww2, const float* __restrict__ bw2,
    const float* __restrict__ Ww3, const float* __restrict__ bw3,
    const float* __restrict__ Ww4, const float* __restrict__ bw4,
    const float* __restrict__ Wp1, const float* __restrict__ bp1,
    const float* __restrict__ Wp2, const float* __restrict__ bp2,
    const float* __restrict__ Wp3, const float* __restrict__ bp3,
    const float* __restrict__ Wp4, const float* __restrict__ bp4)
{
    const int t = threadIdx.x;

    if (blockIdx.x < WBLK) {
        // ---- stage prescaled weights into LDS (broadcast-read thereafter) ----
        __shared__ float sW1[60], sb1[30], sW2[900], sb2[30],
                         sW3[900], sb3[30], sW4[240], sb4[8];
        for (int i = t; i < 900; i += 256) {
            sW2[i] = CEXP * Ww2[i];
            sW3[i] = CEXP * Ww3[i];
        }
        for (int i = t; i < 240; i += 256) sW4[i] = Ww4[i];
        if (t < 60) sW1[t] = CEXP * Ww1[t];
        if (t < 30) {
            sb1[t] = CEXP * bw1[t];
            sb2[t] = CEXP * bw2[t];
            sb3[t] = CEXP * bw3[t];
        }
        if (t < 8) sb4[t] = bw4[t];
        __syncthreads();

        const int gid = blockIdx.x * 256 + t;
        if (gid >= NN * NN) return;
        const int ix = gid % NN, iy = gid / NN;
        const float x0 = (float)ix * (1.0f / (float)NC);
        const float x1 = (float)iy * (1.0f / (float)NC);

        float h[30], a[30];
        #pragma unroll
        for (int j = 0; j < 30; ++j)
            h[j] = tanh_pre(fmaf(x1, sW1[30 + j], fmaf(x0, sW1[j], sb1[j])));

        // layer 2: 30 -> 30 (j-inner, float2 LDS reads)
        #pragma unroll
        for (int j = 0; j < 30; ++j) a[j] = sb2[j];
        #pragma unroll
        for (int k = 0; k < 30; ++k) {
            const float hk = h[k];
            #pragma unroll
            for (int jj = 0; jj < 15; ++jj) {
                const float2 w = *(const float2*)&sW2[k * 30 + 2 * jj];
                a[2 * jj]     = fmaf(hk, w.x, a[2 * jj]);
                a[2 * jj + 1] = fmaf(hk, w.y, a[2 * jj + 1]);
            }
        }
        #pragma unroll
        for (int j = 0; j < 30; ++j) a[j] = tanh_pre(a[j]);

        // layer 3: 30 -> 30
        #pragma unroll
        for (int j = 0; j < 30; ++j) h[j] = sb3[j];
        #pragma unroll
        for (int k = 0; k < 30; ++k) {
            const float ak = a[k];
            #pragma unroll
            for (int jj = 0; jj < 15; ++jj) {
                const float2 w = *(const float2*)&sW3[k * 30 + 2 * jj];
                h[2 * jj]     = fmaf(ak, w.x, h[2 * jj]);
                h[2 * jj + 1] = fmaf(ak, w.y, h[2 * jj + 1]);
            }
        }
        #pragma unroll
        for (int j = 0; j < 30; ++j) h[j] = tanh_pre(h[j]);

        // layer 4: 30 -> 8 (unscaled)
        float o[8];
        #pragma unroll
        for (int j = 0; j < 8; ++j) o[j] = sb4[j];
        #pragma unroll
        for (int k = 0; k < 30; ++k) {
            const float hk = h[k];
            #pragma unroll
            for (int jj = 0; jj < 4; ++jj) {
                const float2 w = *(const float2*)&sW4[k * 8 + 2 * jj];
                o[2 * jj]     = fmaf(hk, w.x, o[2 * jj]);
                o[2 * jj + 1] = fmaf(hk, w.y, o[2 * jj + 1]);
            }
        }
        float4* dst = (float4*)&g_wtab[gid * 8];
        float4 v0; v0.x = o[0]; v0.y = o[1]; v0.z = o[2]; v0.w = o[3];
        float4 v1; v1.x = o[4]; v1.y = o[5]; v1.z = o[6]; v1.w = o[7];
        dst[0] = v0; dst[1] = v1;
        return;
    }

    // ---- s(theta) table blocks ----
    const int cell = (blockIdx.x - WBLK) * 256 + t;
    if (cell < TABN) {
        const float hh = 4.0f / (float)TABN;
        const float p0 = -2.0f + hh * (float)cell;
        const float s0 = s_of_p(p0,      Wp1, bp1, Wp2, bp2, Wp3, bp3, Wp4, bp4);
        const float s1 = s_of_p(p0 + hh, Wp1, bp1, Wp2, bp2, Wp3, bp3, Wp4, bp4);
        float2 e; e.x = s0; e.y = s1 - s0;
        g_stab2[cell] = e;
    }
}

// 2 points per thread. Entire per-point compute is table gathers + ~90 VALU
// ops: bilinear w(x) from the 2-D grid (L2-resident), s(theta) from the 1-D
// table, plus the closed-form geometry/singular-function epilogue.
__global__ __launch_bounds__(256) void interior_kernel(
    const float4* __restrict__ x,      // two points per float4
    const float*  __restrict__ imv,
    const float*  __restrict__ lmbd,
    float* __restrict__ out, int n2)   // n2 = n/2
{
    const int idx = blockIdx.x * blockDim.x + threadIdx.x;
    if (idx >= n2) return;

    const float4 xx = x[idx];
    const float X0[2] = {xx.x, xx.z};
    const float X1[2] = {xx.y, xx.w};
    const float im0 = imv[0], im1 = imv[1], lam = lmbd[0];

    const float4* __restrict__ T = (const float4*)g_wtab;

    float res[2];
    #pragma unroll
    for (int p = 0; p < 2; ++p) {
        const float x0 = X0[p], x1 = X1[p];

        // ---- bilinear gather of w[0..8) from the 2-D grid ----
        const float fx = x0 * (float)NC;
        const float fy = x1 * (float)NC;
        int ix = (int)fx; ix = ix < 0 ? 0 : (ix > NC - 1 ? NC - 1 : ix);
        int iy = (int)fy; iy = iy < 0 ? 0 : (iy > NC - 1 ? NC - 1 : iy);
        const float frx = fx - (float)ix;
        const float fry = fy - (float)iy;

        const int k = (iy * NN + ix) * 2;        // float4 units
        const float4 a0 = T[k],              a1 = T[k + 1];            // (ix  ,iy)
        const float4 b0 = T[k + 2],          b1 = T[k + 3];            // (ix+1,iy)
        const float4 c0 = T[k + NN * 2],     c1 = T[k + NN * 2 + 1];   // (ix  ,iy+1)
        const float4 d0 = T[k + NN * 2 + 2], d1 = T[k + NN * 2 + 3];

        float wv[8];
        {
            const float A[8] = {a0.x, a0.y, a0.z, a0.w, a1.x, a1.y, a1.z, a1.w};
            const float B[8] = {b0.x, b0.y, b0.z, b0.w, b1.x, b1.y, b1.z, b1.w};
            const float C[8] = {c0.x, c0.y, c0.z, c0.w, c1.x, c1.y, c1.z, c1.w};
            const float D[8] = {d0.x, d0.y, d0.z, d0.w, d1.x, d1.y, d1.z, d1.w};
            #pragma unroll
            for (int j = 0; j < 8; ++j) {
                const float r0 = fmaf(frx, B[j] - A[j], A[j]);
                const float r1 = fmaf(frx, D[j] - C[j], C[j]);
                wv[j] = fmaf(fry, r1 - r0, r0);
            }
        }

        // ---- geometry about the interior vertex ----
        const float dx = x0 - im0, dy = x1 - im1;
        const float r  = sqrtf(fmaf(dx, dx, dy * dy));

        // yita(r)
        const float t  = fminf(fmaxf(fmaf(2.5f, r, -1.25f), 0.0f), 1.0f);
        const float t3 = t * t * t;
        const float yv = fmaf(fmaf(fmaf(-6.0f, t, 15.0f), t, -10.0f), t3, 1.0f);

        // r^lambda (sqrt fast path for lambda == 0.5)
        float rl;
        if (lam == 0.5f) rl = sqrtf(r);
        else rl = __builtin_amdgcn_exp2f(lam * __builtin_amdgcn_logf(fmaxf(r, 1e-20f)));

        // diamond-angle parameter p(theta) in [-2,2], no trig
        const float l1n = fmaxf(fabsf(dx) + fabsf(dy), 1e-20f);
        const float u   = dy * __builtin_amdgcn_rcpf(l1n);
        const float pbk = (dy >= 0.0f) ? (2.0f - u) : (-2.0f - u);
        const float pth = (dx >= 0.0f) ? u : pbk;

        // s(theta) table gather: cell {s, ds}, one 8 B load
        const float fi = fminf(fmaxf(fmaf(pth, (float)(TABN / 4), (float)(TABN / 2)),
                                     0.0f), (float)TABN - 0.001f);
        const int   ii = (int)fi;
        const float fr = fi - (float)ii;
        const float2 sd = g_stab2[ii];
        const float sval = fmaf(fr, sd.y, sd.x);

        // singular functions at x (about origin), algebraically reduced:
        // vp0 = r0^0.5 sin(th/2) = copysign(sqrt((r0-x0)/2), x1)
        // vp1 = x1
        // vp2 = r0^1.5 sin(1.5 th) = x1*sqrt((r0+x0)/2) + x0*vp0
        const float r0 = sqrtf(fmaf(x0, x0, x1 * x1));
        const float A  = sqrtf(fmaxf(0.0f, (r0 - x0) * 0.5f));
        const float Bq = sqrtf(fmaxf(0.0f, (r0 + x0) * 0.5f));
        const float vp0 = copysignf(A, x1);
        const float vp2 = fmaf(x1, Bq, x0 * vp0);

        // combine
        float rp = fmaf(yv, wv[4], wv[0]);
        rp = fmaf(fmaf(wv[5], yv, wv[1]), vp0, rp);
        rp = fmaf(fmaf(wv[6], yv, wv[2]), x1, rp);
        rp = fmaf(fmaf(wv[7], yv, wv[3]), vp2, rp);
        res[p] = fmaf(sval * yv, rl, rp);
    }

    float2 o; o.x = res[0]; o.y = res[1];
    ((float2*)out)[idx] = o;
}

extern "C" void kernel_launch(void* const* d_in, const int* in_sizes, int n_in,
                              void* d_out, int out_size, void* d_ws, size_t ws_size,
                              hipStream_t stream) {
    const float4* x   = (const float4*)d_in[0];
    const float* imv  = (const float*)d_in[1];
    const float* lmbd = (const float*)d_in[2];
    const float* Ww1  = (const float*)d_in[3];
    const float* bw1  = (const float*)d_in[4];
    const float* Ww2  = (const float*)d_in[5];
    const float* bw2  = (const float*)d_in[6];
    const float* Ww3  = (const float*)d_in[7];
    const float* bw3  = (const float*)d_in[8];
    const float* Ww4  = (const float*)d_in[9];
    const float* bw4  = (const float*)d_in[10];
    const float* Wp1  = (const float*)d_in[11];
    const float* bp1  = (const float*)d_in[12];
    const float* Wp2  = (const float*)d_in[13];
    const float* bp2  = (const float*)d_in[14];
    const float* Wp3  = (const float*)d_in[15];
    const float* bp3  = (const float*)d_in[16];
    const float* Wp4  = (const float*)d_in[17];
    const float* bp4  = (const float*)d_in[18];
    float* out = (float*)d_out;

    const int n  = in_sizes[0] / 2;
    const int n2 = n / 2;

    // WBLK blocks for the w-grid + 8 blocks for the s-table.
    prep_kernel<<<WBLK + (TABN + 255) / 256, 256, 0, stream>>>(
        Ww1, bw1, Ww2, bw2, Ww3, bw3, Ww4, bw4,
        Wp1, bp1, Wp2, bp2, Wp3, bp3, Wp4, bp4);

    const int block = 256;
    const int grid = (n2 + block - 1) / block;
    interior_kernel<<<grid, block, 0, stream>>>(x, imv, lmbd, out, n2);
}